// Round 1
// baseline (96.789 us; speedup 1.0000x reference)
//
#include <hip/hip_runtime.h>
#include <math.h>

// Problem constants (fixed by the reference)
#define NSTEPS 32
#define DT_C   (1.0f/32.0f)
#define MU_C   0.05f
#define SIG_C  0.2f
#define T0_C   0.0f

// Lookup table: f(x)=net_y(T0,x) and tanh(x) sampled on [-16,16], 4096 pts.
#define NENT  4096
#define XMIN  (-16.0f)
#define HSTEP (1.0f/128.0f)      // 32 / 4096
#define INVH  128.0f

// ---------------------------------------------------------------------------
// Kernel 1: build the table. One wave per entry-group; lane j owns hidden
// unit j. h1 broadcast across the wave via __shfl (readlane), W2 column held
// in per-lane registers (loaded coalesced: lane j reads W2[k*64+j]).
// ---------------------------------------------------------------------------
__global__ __launch_bounds__(256) void build_table(
    const float* __restrict__ W1, const float* __restrict__ b1,
    const float* __restrict__ W2, const float* __restrict__ b2,
    const float* __restrict__ W3, const float* __restrict__ b3,
    float2* __restrict__ tab)
{
    const int lane = threadIdx.x & 63;
    const int wave = (blockIdx.x * blockDim.x + threadIdx.x) >> 6;   // 1024 waves

    const float w1b = W1[64 + lane];                  // W1[1][lane]
    const float c1  = fmaf(T0_C, W1[lane], b1[lane]); // t-term (t = T0 = 0)
    const float b2j = b2[lane];
    const float w3j = W3[2 * lane];                   // W3[lane][0]
    const float b30 = b3[0];

    float w2col[64];
    #pragma unroll
    for (int k = 0; k < 64; ++k) w2col[k] = W2[k * 64 + lane];  // coalesced per k

    #pragma unroll
    for (int q = 0; q < 4; ++q) {                     // 1024 waves * 4 = 4096 entries
        const int e = wave * 4 + q;
        const float x = XMIN + (float)e * HSTEP;
        const float h1 = tanhf(fmaf(x, w1b, c1));
        float acc = b2j;
        #pragma unroll
        for (int k = 0; k < 64; ++k) {
            const float hk = __shfl(h1, k, 64);       // v_readlane broadcast
            acc = fmaf(hk, w2col[k], acc);
        }
        float part = tanhf(acc) * w3j;
        #pragma unroll
        for (int m = 1; m < 64; m <<= 1) part += __shfl_xor(part, m, 64);
        if (lane == 0) tab[e] = make_float2(part + b30, tanhf(x));
    }
}

// ---------------------------------------------------------------------------
// Kernel 2: one thread per path. Table staged in LDS (32 KiB). 32 fully
// unrolled Euler steps; each step: 1 lerp lookup (y, tanh(x)) + tamed-drift
// x update + y_lin update + loss accumulation. Wave-reduce + 1 atomic/wave.
// ---------------------------------------------------------------------------
__global__ __launch_bounds__(256) void paths_kernel(
    const float* __restrict__ x0, const float* __restrict__ dW,
    const float2* __restrict__ tabg, float* __restrict__ out,
    const float invNB, const float invB)
{
    __shared__ float2 tab[NENT];
    const int tid = threadIdx.x;
    {
        const float4* src = (const float4*)tabg;
        float4* dst = (float4*)tab;
        #pragma unroll
        for (int i = 0; i < 8; ++i)                   // 2048 float4 / 256 threads
            dst[tid + i * 256] = src[tid + i * 256];
    }
    __syncthreads();

    const int p = blockIdx.x * 256 + tid;
    float x    = x0[p];
    float ylin = 1.0f;
    float lacc = 0.0f;

    float4 d4[8];
    const float4* dwp = (const float4*)(dW + (size_t)p * NSTEPS);
    #pragma unroll
    for (int i = 0; i < 8; ++i) d4[i] = dwp[i];
    const float* dws = (const float*)d4;

    #pragma unroll
    for (int n = 0; n < NSTEPS; ++n) {
        const float dwn = dws[n];
        // table lookup for y(x), tanh(x)
        float u = fmaf(x, INVH, -XMIN * INVH);
        u = fminf(fmaxf(u, 0.0f), (float)(NENT - 1) - 0.001f);
        const int   i0 = (int)u;
        const float fr = u - (float)i0;
        const float2 e0 = tab[i0];
        const float2 e1 = tab[i0 + 1];
        const float y  = fmaf(fr, e1.x - e0.x, e0.x);
        const float tx = fmaf(fr, e1.y - e0.y, e0.y);
        // loss term (uses pre-update ylin)
        const float ycv = y - ylin;
        lacc = fmaf(ycv, ycv, lacc);
        // tamed drift + Euler step (uses pre-update x)
        float mu = MU_C * x;
        const float den = fmaf(DT_C, fabsf(mu), 1.0f);
        mu = mu * __builtin_amdgcn_rcpf(den);
        const float xs = SIG_C * x;
        float xn = fmaf(mu, DT_C, x);
        x = fmaf(xs, dwn, xn);
        // control-variate linear state
        ylin = fmaf(-DT_C, tx, ylin);
    }

    float val = fmaf(lacc, invNB, 0.01f * ylin * ylin * invB);
    #pragma unroll
    for (int off = 32; off >= 1; off >>= 1) val += __shfl_down(val, off, 64);
    if ((tid & 63) == 0) atomicAdd(out, val);
}

// ---------------------------------------------------------------------------
extern "C" void kernel_launch(void* const* d_in, const int* in_sizes, int n_in,
                              void* d_out, int out_size, void* d_ws, size_t ws_size,
                              hipStream_t stream) {
    const float* x0 = (const float*)d_in[0];
    const float* dW = (const float*)d_in[1];
    const float* W1 = (const float*)d_in[2];
    const float* b1 = (const float*)d_in[3];
    const float* W2 = (const float*)d_in[4];
    const float* b2 = (const float*)d_in[5];
    const float* W3 = (const float*)d_in[6];
    const float* b3 = (const float*)d_in[7];

    float2* tab = (float2*)d_ws;           // 4096 * 8 B = 32 KiB of workspace
    float*  out = (float*)d_out;
    const int B = in_sizes[0];             // 65536

    hipMemsetAsync(out, 0, sizeof(float), stream);   // d_out is poisoned 0xAA

    build_table<<<256, 256, 0, stream>>>(W1, b1, W2, b2, W3, b3, tab);

    const float invNB = 1.0f / ((float)NSTEPS * (float)B);
    const float invB  = 1.0f / (float)B;
    paths_kernel<<<B / 256, 256, 0, stream>>>(x0, dW, tab, out, invNB, invB);
}

// Round 2
// 85.559 us; speedup vs baseline: 1.1312x; 1.1312x over previous
//
#include <hip/hip_runtime.h>
#include <math.h>

// Problem constants (fixed by the reference)
#define NSTEPS 32
#define DT_C   (1.0f/32.0f)
#define MU_C   0.05f
#define SIG_C  0.2f
#define T0_C   0.0f

// Lookup table: f(x)=net_y(T0,x) and tanh(x) sampled on [-16,16], 4096 pts.
#define NENT  4096
#define XMIN  (-16.0f)
#define HSTEP (1.0f/128.0f)      // 32 / 4096
#define INVH  128.0f

#define NBLK  256                 // paths_kernel grid (65536 / 256)

// ---------------------------------------------------------------------------
// Kernel 1: build the table. One wave per entry-group; lane j owns hidden
// unit j. h1 broadcast across the wave via readlane-shfl, W2 column held in
// per-lane registers (loaded coalesced: lane j reads W2[k*64+j]).
// ---------------------------------------------------------------------------
__global__ __launch_bounds__(256) void build_table(
    const float* __restrict__ W1, const float* __restrict__ b1,
    const float* __restrict__ W2, const float* __restrict__ b2,
    const float* __restrict__ W3, const float* __restrict__ b3,
    float2* __restrict__ tab)
{
    const int lane = threadIdx.x & 63;
    const int wave = (blockIdx.x * blockDim.x + threadIdx.x) >> 6;   // 1024 waves

    const float w1b = W1[64 + lane];                  // W1[1][lane]
    const float c1  = fmaf(T0_C, W1[lane], b1[lane]); // t-term (t = T0 = 0)
    const float b2j = b2[lane];
    const float w3j = W3[2 * lane];                   // W3[lane][0]
    const float b30 = b3[0];

    float w2col[64];
    #pragma unroll
    for (int k = 0; k < 64; ++k) w2col[k] = W2[k * 64 + lane];  // coalesced per k

    #pragma unroll
    for (int q = 0; q < 4; ++q) {                     // 1024 waves * 4 = 4096 entries
        const int e = wave * 4 + q;
        const float x = XMIN + (float)e * HSTEP;
        const float h1 = tanhf(fmaf(x, w1b, c1));
        float acc = b2j;
        #pragma unroll
        for (int k = 0; k < 64; ++k) {
            const float hk = __shfl(h1, k, 64);       // v_readlane broadcast
            acc = fmaf(hk, w2col[k], acc);
        }
        float part = tanhf(acc) * w3j;
        #pragma unroll
        for (int m = 1; m < 64; m <<= 1) part += __shfl_xor(part, m, 64);
        if (lane == 0) tab[e] = make_float2(part + b30, tanhf(x));
    }
}

// ---------------------------------------------------------------------------
// Kernel 2: one thread per path. Table staged in LDS (32 KiB). 32 fully
// unrolled Euler steps. Block-level tree reduction -> ONE plain store per
// block (no atomics: 1024 same-address atomicAdds serialized cross-XCD and
// cost ~100 us in R1).
// ---------------------------------------------------------------------------
__global__ __launch_bounds__(256) void paths_kernel(
    const float* __restrict__ x0, const float* __restrict__ dW,
    const float2* __restrict__ tabg, float* __restrict__ part,
    const float invNB, const float invB)
{
    __shared__ float2 tab[NENT];
    __shared__ float sred[4];
    const int tid = threadIdx.x;
    {
        const float4* src = (const float4*)tabg;
        float4* dst = (float4*)tab;
        #pragma unroll
        for (int i = 0; i < 8; ++i)                   // 2048 float4 / 256 threads
            dst[tid + i * 256] = src[tid + i * 256];
    }
    __syncthreads();

    const int p = blockIdx.x * 256 + tid;
    float x    = x0[p];
    float ylin = 1.0f;
    float lacc = 0.0f;

    float4 d4[8];
    const float4* dwp = (const float4*)(dW + (size_t)p * NSTEPS);
    #pragma unroll
    for (int i = 0; i < 8; ++i) d4[i] = dwp[i];
    const float* dws = (const float*)d4;

    #pragma unroll
    for (int n = 0; n < NSTEPS; ++n) {
        const float dwn = dws[n];
        // table lookup for y(x), tanh(x)
        float u = fmaf(x, INVH, -XMIN * INVH);
        u = fminf(fmaxf(u, 0.0f), (float)(NENT - 1) - 0.001f);
        const int   i0 = (int)u;
        const float fr = u - (float)i0;
        const float2 e0 = tab[i0];
        const float2 e1 = tab[i0 + 1];
        const float y  = fmaf(fr, e1.x - e0.x, e0.x);
        const float tx = fmaf(fr, e1.y - e0.y, e0.y);
        // loss term (uses pre-update ylin)
        const float ycv = y - ylin;
        lacc = fmaf(ycv, ycv, lacc);
        // tamed drift + Euler step (uses pre-update x)
        float mu = MU_C * x;
        const float den = fmaf(DT_C, fabsf(mu), 1.0f);
        mu = mu * __builtin_amdgcn_rcpf(den);
        const float xs = SIG_C * x;
        float xn = fmaf(mu, DT_C, x);
        x = fmaf(xs, dwn, xn);
        // control-variate linear state
        ylin = fmaf(-DT_C, tx, ylin);
    }

    float val = fmaf(lacc, invNB, 0.01f * ylin * ylin * invB);
    #pragma unroll
    for (int off = 32; off >= 1; off >>= 1) val += __shfl_down(val, off, 64);
    if ((tid & 63) == 0) sred[tid >> 6] = val;
    __syncthreads();
    if (tid == 0) part[blockIdx.x] = sred[0] + sred[1] + sred[2] + sred[3];
}

// ---------------------------------------------------------------------------
// Kernel 3: reduce 256 block-partials, plain store to d_out (no memset needed).
// ---------------------------------------------------------------------------
__global__ __launch_bounds__(256) void reduce_partials(
    const float* __restrict__ part, float* __restrict__ out)
{
    __shared__ float s[4];
    const int tid = threadIdx.x;
    float v = part[tid];
    #pragma unroll
    for (int off = 32; off >= 1; off >>= 1) v += __shfl_down(v, off, 64);
    if ((tid & 63) == 0) s[tid >> 6] = v;
    __syncthreads();
    if (tid == 0) out[0] = s[0] + s[1] + s[2] + s[3];
}

// ---------------------------------------------------------------------------
extern "C" void kernel_launch(void* const* d_in, const int* in_sizes, int n_in,
                              void* d_out, int out_size, void* d_ws, size_t ws_size,
                              hipStream_t stream) {
    const float* x0 = (const float*)d_in[0];
    const float* dW = (const float*)d_in[1];
    const float* W1 = (const float*)d_in[2];
    const float* b1 = (const float*)d_in[3];
    const float* W2 = (const float*)d_in[4];
    const float* b2 = (const float*)d_in[5];
    const float* W3 = (const float*)d_in[6];
    const float* b3 = (const float*)d_in[7];

    float2* tab  = (float2*)d_ws;                       // 32 KiB
    float*  part = (float*)((char*)d_ws + NENT * 8);    // 256 floats after table
    float*  out  = (float*)d_out;
    const int B = in_sizes[0];                          // 65536

    build_table<<<256, 256, 0, stream>>>(W1, b1, W2, b2, W3, b3, tab);

    const float invNB = 1.0f / ((float)NSTEPS * (float)B);
    const float invB  = 1.0f / (float)B;
    paths_kernel<<<B / 256, 256, 0, stream>>>(x0, dW, tab, part, invNB, invB);
    reduce_partials<<<1, 256, 0, stream>>>(part, out);
}